// Round 1
// baseline (392.963 us; speedup 1.0000x reference)
//
#include <hip/hip_runtime.h>
#include <cstdint>

// Dims (fixed per setup_inputs): B=8, H=128, D=512, L=128, V=2D=1024, inner=384
#define B_ 8
#define H_ 128
#define D_ 512
#define L_ 128
#define V_ 1024

// ---------------- Kernel 1: argmax(|d_x|) + gather -> pv [B,H,V] ----------------
// One wave (64 lanes) per (b,h,d) row of 127 diffs.
__global__ __launch_bounds__(256) void k_pool(const float* __restrict__ x,
                                              const float* __restrict__ dx,
                                              float* __restrict__ pv) {
  int64_t wave = (int64_t)blockIdx.x * 4 + (threadIdx.x >> 6);
  int lane = threadIdx.x & 63;
  const float* drow = dx + wave * 127;
  float bv = fabsf(drow[lane]);
  int bi = lane;
  if (lane < 63) {
    float v1 = fabsf(drow[lane + 64]);
    if (v1 > bv) { bv = v1; bi = lane + 64; }  // tie keeps lower idx
  }
#pragma unroll
  for (int off = 1; off < 64; off <<= 1) {
    float ov = __shfl_xor(bv, off, 64);
    int   oi = __shfl_xor(bi, off, 64);
    if (ov > bv || (ov == bv && oi < bi)) { bv = ov; bi = oi; }
  }
  if (lane == 0) {
    const float* xrow = x + wave * L_;
    float2 o;
    o.x = xrow[bi];
    o.y = xrow[bi + 1];
    int64_t bh = wave >> 9;           // (b*H+h)
    int d = (int)(wave & 511);
    *(float2*)(pv + (bh << 10) + 2 * d) = o;  // v = 2d, 2d+1
  }
}

// ---------------- Kernel 2: adj = pv^T pv / V, mask, leaky, softmax, +I ----------------
// Block handles 8 rows (v0..v0+7) of A[b]; 256 threads each own 4 consecutive w.
__global__ __launch_bounds__(256) void k_adj(const float* __restrict__ pv,
                                             float* __restrict__ A) {
  const int b  = blockIdx.x >> 7;
  const int v0 = (blockIdx.x & 127) * 8;
  const float* pvb = pv + ((int64_t)b << 17);  // b*128*1024
  __shared__ float cols[128][8];
  __shared__ float wred[8][4];
  const int tid = threadIdx.x;
  for (int e = tid; e < 1024; e += 256)
    cols[e >> 3][e & 7] = pvb[(int64_t)(e >> 3) * 1024 + v0 + (e & 7)];
  __syncthreads();

  float acc[4][8];
#pragma unroll
  for (int k = 0; k < 4; ++k)
#pragma unroll
    for (int j = 0; j < 8; ++j) acc[k][j] = 0.f;

  for (int h = 0; h < 128; ++h) {
    float4 pvv = *(const float4*)(pvb + h * 1024 + (tid << 2));
    float c8[8];
#pragma unroll
    for (int j = 0; j < 8; ++j) c8[j] = cols[h][j];
    float pk[4] = {pvv.x, pvv.y, pvv.z, pvv.w};
#pragma unroll
    for (int k = 0; k < 4; ++k)
#pragma unroll
      for (int j = 0; j < 8; ++j) acc[k][j] = fmaf(pk[k], c8[j], acc[k][j]);
  }

  const int lane = tid & 63, wid = tid >> 6;
  float rmax[8], rsum[8];
#pragma unroll
  for (int j = 0; j < 8; ++j) {
    float lm = -1e30f;
#pragma unroll
    for (int k = 0; k < 4; ++k) {
      int w = (tid << 2) + k;
      float a = acc[k][j] * (1.0f / 1024.0f);
      if (w == v0 + j) a -= 1e8f;         // - eye*MASK_VAL
      a = (a > 0.f) ? a : 0.01f * a;      // leaky_relu
      acc[k][j] = a;
      lm = fmaxf(lm, a);
    }
#pragma unroll
    for (int off = 1; off < 64; off <<= 1) lm = fmaxf(lm, __shfl_xor(lm, off, 64));
    if (lane == 0) wred[j][wid] = lm;
  }
  __syncthreads();
#pragma unroll
  for (int j = 0; j < 8; ++j)
    rmax[j] = fmaxf(fmaxf(wred[j][0], wred[j][1]), fmaxf(wred[j][2], wred[j][3]));
  __syncthreads();
#pragma unroll
  for (int j = 0; j < 8; ++j) {
    float ls = 0.f;
#pragma unroll
    for (int k = 0; k < 4; ++k) {
      float e = __expf(acc[k][j] - rmax[j]);
      acc[k][j] = e;
      ls += e;
    }
#pragma unroll
    for (int off = 1; off < 64; off <<= 1) ls += __shfl_xor(ls, off, 64);
    if (lane == 0) wred[j][wid] = ls;
  }
  __syncthreads();
#pragma unroll
  for (int j = 0; j < 8; ++j)
    rsum[j] = 1.0f / (wred[j][0] + wred[j][1] + wred[j][2] + wred[j][3]);

  float* Ab = A + (((int64_t)b << 10) + v0) * 1024;
#pragma unroll
  for (int j = 0; j < 8; ++j) {
    float4 o;
    float* po = &o.x;
#pragma unroll
    for (int k = 0; k < 4; ++k) {
      int w = (tid << 2) + k;
      po[k] = acc[k][j] * rsum[j] + ((w == v0 + j) ? 1.0f : 0.0f);  // + eye
    }
    *(float4*)(Ab + (int64_t)j * 1024 + (tid << 2)) = o;
  }
}

// ---------------- Kernel 3: Y[b] = X[b] (128x1024) @ A[b] (1024x1024) ----------------
// BM=32, BN=128, BK=32; 256 threads, 4x4 per thread. Grid = 8*4*8 = 256.
__global__ __launch_bounds__(256) void k_gemm_xA(const float* __restrict__ X,
                                                 const float* __restrict__ Am,
                                                 float* __restrict__ Y) {
  const int bid = blockIdx.x;
  const int b  = bid >> 5;
  const int m0 = ((bid >> 3) & 3) * 32;
  const int n0 = (bid & 7) * 128;
  const float* Xb = X + ((int64_t)b << 17);
  const float* Ab = Am + ((int64_t)b << 20);
  __shared__ float As[32][33];
  __shared__ float Bs[32][128];
  const int tid = threadIdx.x;
  const int ty = tid >> 5, tx = tid & 31;
  float acc[4][4] = {{0.f}};
  for (int k0 = 0; k0 < 1024; k0 += 32) {
    {
      int r = tid >> 3, c = (tid & 7) << 2;
      float4 v = *(const float4*)(Xb + (int64_t)(m0 + r) * 1024 + k0 + c);
      As[r][c] = v.x; As[r][c + 1] = v.y; As[r][c + 2] = v.z; As[r][c + 3] = v.w;
    }
#pragma unroll
    for (int q = 0; q < 4; ++q) {
      int r = (tid >> 5) + (q << 3);
      *(float4*)(&Bs[r][tx << 2]) =
          *(const float4*)(Ab + (int64_t)(k0 + r) * 1024 + n0 + (tx << 2));
    }
    __syncthreads();
#pragma unroll
    for (int kk = 0; kk < 32; ++kk) {
      float a_[4], b_[4];
#pragma unroll
      for (int i = 0; i < 4; ++i) a_[i] = As[ty + (i << 3)][kk];
#pragma unroll
      for (int j = 0; j < 4; ++j) b_[j] = Bs[kk][tx + (j << 5)];
#pragma unroll
      for (int i = 0; i < 4; ++i)
#pragma unroll
        for (int j = 0; j < 4; ++j) acc[i][j] = fmaf(a_[i], b_[j], acc[i][j]);
    }
    __syncthreads();
  }
#pragma unroll
  for (int i = 0; i < 4; ++i)
#pragma unroll
    for (int j = 0; j < 4; ++j)
      Y[((int64_t)b << 17) + (int64_t)(m0 + ty + (i << 3)) * 1024 + n0 + tx + (j << 5)] =
          acc[i][j];
}

// ---------------- Kernel 4: hpre[b] = W (128x384) @ concat[x0;x1;x2][b] (384x1024) + bias ----------------
__global__ __launch_bounds__(256) void k_conv(const float* __restrict__ pv,
                                              const float* __restrict__ x1,
                                              const float* __restrict__ x2,
                                              const float* __restrict__ W,
                                              const float* __restrict__ bias,
                                              float* __restrict__ hpre) {
  const int bid = blockIdx.x;
  const int b  = bid >> 5;
  const int m0 = ((bid >> 3) & 3) * 32;
  const int n0 = (bid & 7) * 128;
  const float* s0 = pv + ((int64_t)b << 17);
  const float* s1 = x1 + ((int64_t)b << 17);
  const float* s2 = x2 + ((int64_t)b << 17);
  __shared__ float As[32][33];
  __shared__ float Bs[32][128];
  const int tid = threadIdx.x;
  const int ty = tid >> 5, tx = tid & 31;
  float acc[4][4] = {{0.f}};
  for (int k0 = 0; k0 < 384; k0 += 32) {
    {
      int r = tid >> 3, c = (tid & 7) << 2;
      float4 v = *(const float4*)(W + (int64_t)(m0 + r) * 384 + k0 + c);
      As[r][c] = v.x; As[r][c + 1] = v.y; As[r][c + 2] = v.z; As[r][c + 3] = v.w;
    }
#pragma unroll
    for (int q = 0; q < 4; ++q) {
      int r = (tid >> 5) + (q << 3);
      int i = k0 + r;
      const float* src = (i < 128) ? s0 : ((i < 256) ? s1 : s2);
      *(float4*)(&Bs[r][tx << 2]) =
          *(const float4*)(src + (int64_t)(i & 127) * 1024 + n0 + (tx << 2));
    }
    __syncthreads();
#pragma unroll
    for (int kk = 0; kk < 32; ++kk) {
      float a_[4], b_[4];
#pragma unroll
      for (int i = 0; i < 4; ++i) a_[i] = As[ty + (i << 3)][kk];
#pragma unroll
      for (int j = 0; j < 4; ++j) b_[j] = Bs[kk][tx + (j << 5)];
#pragma unroll
      for (int i = 0; i < 4; ++i)
#pragma unroll
        for (int j = 0; j < 4; ++j) acc[i][j] = fmaf(a_[i], b_[j], acc[i][j]);
    }
    __syncthreads();
  }
#pragma unroll
  for (int i = 0; i < 4; ++i) {
    int o = m0 + ty + (i << 3);
    float bs = bias[o];
#pragma unroll
    for (int j = 0; j < 4; ++j)
      hpre[((int64_t)b * 128 + o) * 1024 + n0 + tx + (j << 5)] = acc[i][j] + bs;
  }
}

// ---------------- Kernel 5: per-channel BN stats (deterministic) ----------------
__global__ __launch_bounds__(256) void k_stats(const float* __restrict__ hpre,
                                               const float* __restrict__ gamma,
                                               const float* __restrict__ beta,
                                               float2* __restrict__ ss) {
  const int o = blockIdx.x;
  const int tid = threadIdx.x;
  float s = 0.f, s2 = 0.f;
  for (int e = tid; e < 8192; e += 256) {
    int bb = e >> 10, v = e & 1023;
    float val = hpre[((int64_t)(bb * 128 + o) << 10) + v];
    s += val;
    s2 = fmaf(val, val, s2);
  }
#pragma unroll
  for (int off = 1; off < 64; off <<= 1) {
    s  += __shfl_xor(s, off, 64);
    s2 += __shfl_xor(s2, off, 64);
  }
  __shared__ float rs[4], rs2[4];
  int lane = tid & 63, wid = tid >> 6;
  if (lane == 0) { rs[wid] = s; rs2[wid] = s2; }
  __syncthreads();
  if (tid == 0) {
    float S  = rs[0] + rs[1] + rs[2] + rs[3];
    float S2 = rs2[0] + rs2[1] + rs2[2] + rs2[3];
    float mean = S * (1.0f / 8192.0f);
    float var  = S2 * (1.0f / 8192.0f) - mean * mean;
    float istd = rsqrtf(var + 1e-5f);
    float scale = gamma[o] * istd;
    ss[o] = make_float2(scale, beta[o] - mean * scale);
  }
}

// ---------------- Kernel 6: BN apply + output permutation ----------------
// out[b, p*128+h, d] = hpre[b, h, 2d+p]*scale[h] + shift[h]
__global__ __launch_bounds__(256) void k_out(const float* __restrict__ hpre,
                                             const float2* __restrict__ ss,
                                             float* __restrict__ out) {
  int64_t idx = (int64_t)blockIdx.x * 256 + threadIdx.x;  // 1,048,576 total
  int d  = (int)(idx & 511);
  int ph = (int)((idx >> 9) & 255);
  int b  = (int)(idx >> 17);
  int p = ph >> 7, h = ph & 127;
  float2 sc = ss[h];
  float val = hpre[(((int64_t)b * 128 + h) << 10) + 2 * d + p];
  out[idx] = fmaf(val, sc.x, sc.y);
}

extern "C" void kernel_launch(void* const* d_in, const int* in_sizes, int n_in,
                              void* d_out, int out_size, void* d_ws, size_t ws_size,
                              hipStream_t stream) {
  const float* x     = (const float*)d_in[0];
  const float* dx    = (const float*)d_in[1];
  const float* W     = (const float*)d_in[2];
  const float* cb    = (const float*)d_in[3];
  const float* gamma = (const float*)d_in[4];
  const float* beta  = (const float*)d_in[5];

  float* ws   = (float*)d_ws;
  float* pv   = ws;                 // 1,048,576 floats
  float* Am   = pv + 1048576;       // 8,388,608 floats
  float* x1   = Am + 8388608;       // 1,048,576
  float* x2   = x1 + 1048576;       // 1,048,576
  float* hpre = x2 + 1048576;       // 1,048,576
  float2* ssb = (float2*)(hpre + 1048576);  // 128 float2
  float* out  = (float*)d_out;

  k_pool<<<131072, 256, 0, stream>>>(x, dx, pv);
  k_adj<<<1024, 256, 0, stream>>>(pv, Am);
  k_gemm_xA<<<256, 256, 0, stream>>>(pv, Am, x1);
  k_gemm_xA<<<256, 256, 0, stream>>>(x1, Am, x2);
  k_conv<<<256, 256, 0, stream>>>(pv, x1, x2, W, cb, hpre);
  k_stats<<<128, 256, 0, stream>>>(hpre, gamma, beta, ssb);
  k_out<<<4096, 256, 0, stream>>>(hpre, ssb, out);
}

// Round 2
// 317.006 us; speedup vs baseline: 1.2396x; 1.2396x over previous
//
#include <hip/hip_runtime.h>
#include <cstdint>

// Dims (fixed per setup_inputs): B=8, H=128, D=512, L=128, V=2D=1024, inner=384
#define B_ 8
#define H_ 128
#define D_ 512
#define L_ 128
#define V_ 1024

// ---------------- Kernel 1: argmax(|d_x|) + gather -> pv [B,H,V] ----------------
// One THREAD per (b,h,d) row of 127 diffs. 256-thread block = 256 contiguous rows.
// dx region per block is contiguous (256*127 floats): load flat-coalesced in
// 32-col tiles into LDS[256][33] (odd stride -> conflict-free both phases),
// then each thread scans its row with a strict-> running argmax (first max wins,
// matching np.argmax tie semantics).
__global__ __launch_bounds__(256) void k_pool(const float* __restrict__ x,
                                              const float* __restrict__ dx,
                                              float* __restrict__ pv) {
  __shared__ float lds[256][33];
  const int tid = threadIdx.x;
  const int64_t rowbase = (int64_t)blockIdx.x * 256;
  const float* dblk = dx + rowbase * 127;

  float bv = -1.0f;
  int bi = 0;

#pragma unroll
  for (int c0 = 0; c0 < 127; c0 += 32) {
    const int tw = (c0 == 96) ? 31 : 32;
    __syncthreads();
    // cooperative load: 256 threads x 32 elems = [256 rows][32 cols] tile
#pragma unroll
    for (int i = 0; i < 32; ++i) {
      int e = tid + (i << 8);          // 0..8191
      int r = e >> 5;
      int cl = e & 31;
      int c = c0 + cl;
      lds[r][cl] = (c < 127) ? dblk[(int64_t)r * 127 + c] : 0.0f;
    }
    __syncthreads();
    for (int k = 0; k < tw; ++k) {
      float a = fabsf(lds[tid][k]);
      if (a > bv) { bv = a; bi = c0 + k; }
    }
  }

  const int64_t row = rowbase + tid;
  const float* xr = x + row * L_;
  float2 o;
  o.x = xr[bi];
  o.y = xr[bi + 1];
  int64_t bh = row >> 9;               // (b*H+h)
  int d = (int)(row & 511);
  *(float2*)(pv + (bh << 10) + 2 * d) = o;
}

// ---------------- Kernel 2: adj = pv^T pv / V, mask, leaky, softmax, +I ----------------
// Block handles 8 rows (v0..v0+7) of A[b]; 256 threads each own 4 consecutive w.
__global__ __launch_bounds__(256) void k_adj(const float* __restrict__ pv,
                                             float* __restrict__ A) {
  const int b  = blockIdx.x >> 7;
  const int v0 = (blockIdx.x & 127) * 8;
  const float* pvb = pv + ((int64_t)b << 17);  // b*128*1024
  __shared__ float cols[128][8];
  __shared__ float wred[8][4];
  const int tid = threadIdx.x;
  for (int e = tid; e < 1024; e += 256)
    cols[e >> 3][e & 7] = pvb[(int64_t)(e >> 3) * 1024 + v0 + (e & 7)];
  __syncthreads();

  float acc[4][8];
#pragma unroll
  for (int k = 0; k < 4; ++k)
#pragma unroll
    for (int j = 0; j < 8; ++j) acc[k][j] = 0.f;

  for (int h = 0; h < 128; ++h) {
    float4 pvv = *(const float4*)(pvb + h * 1024 + (tid << 2));
    float c8[8];
#pragma unroll
    for (int j = 0; j < 8; ++j) c8[j] = cols[h][j];
    float pk[4] = {pvv.x, pvv.y, pvv.z, pvv.w};
#pragma unroll
    for (int k = 0; k < 4; ++k)
#pragma unroll
      for (int j = 0; j < 8; ++j) acc[k][j] = fmaf(pk[k], c8[j], acc[k][j]);
  }

  const int lane = tid & 63, wid = tid >> 6;
  float rmax[8], rsum[8];
#pragma unroll
  for (int j = 0; j < 8; ++j) {
    float lm = -1e30f;
#pragma unroll
    for (int k = 0; k < 4; ++k) {
      int w = (tid << 2) + k;
      float a = acc[k][j] * (1.0f / 1024.0f);
      if (w == v0 + j) a -= 1e8f;         // - eye*MASK_VAL
      a = (a > 0.f) ? a : 0.01f * a;      // leaky_relu
      acc[k][j] = a;
      lm = fmaxf(lm, a);
    }
#pragma unroll
    for (int off = 1; off < 64; off <<= 1) lm = fmaxf(lm, __shfl_xor(lm, off, 64));
    if (lane == 0) wred[j][wid] = lm;
  }
  __syncthreads();
#pragma unroll
  for (int j = 0; j < 8; ++j)
    rmax[j] = fmaxf(fmaxf(wred[j][0], wred[j][1]), fmaxf(wred[j][2], wred[j][3]));
  __syncthreads();
#pragma unroll
  for (int j = 0; j < 8; ++j) {
    float ls = 0.f;
#pragma unroll
    for (int k = 0; k < 4; ++k) {
      float e = __expf(acc[k][j] - rmax[j]);
      acc[k][j] = e;
      ls += e;
    }
#pragma unroll
    for (int off = 1; off < 64; off <<= 1) ls += __shfl_xor(ls, off, 64);
    if (lane == 0) wred[j][wid] = ls;
  }
  __syncthreads();
#pragma unroll
  for (int j = 0; j < 8; ++j)
    rsum[j] = 1.0f / (wred[j][0] + wred[j][1] + wred[j][2] + wred[j][3]);

  float* Ab = A + (((int64_t)b << 10) + v0) * 1024;
#pragma unroll
  for (int j = 0; j < 8; ++j) {
    float4 o;
    float* po = &o.x;
#pragma unroll
    for (int k = 0; k < 4; ++k) {
      int w = (tid << 2) + k;
      po[k] = acc[k][j] * rsum[j] + ((w == v0 + j) ? 1.0f : 0.0f);  // + eye
    }
    *(float4*)(Ab + (int64_t)j * 1024 + (tid << 2)) = o;
  }
}

// ---------------- Kernel 3: Y[b] = X[b] (128x1024) @ A[b] (1024x1024) ----------------
// BM=32, BN=128, BK=32; 256 threads, 4x4 per thread. Grid = 8*4*8 = 256.
__global__ __launch_bounds__(256) void k_gemm_xA(const float* __restrict__ X,
                                                 const float* __restrict__ Am,
                                                 float* __restrict__ Y) {
  const int bid = blockIdx.x;
  const int b  = bid >> 5;
  const int m0 = ((bid >> 3) & 3) * 32;
  const int n0 = (bid & 7) * 128;
  const float* Xb = X + ((int64_t)b << 17);
  const float* Ab = Am + ((int64_t)b << 20);
  __shared__ float As[32][33];
  __shared__ float Bs[32][128];
  const int tid = threadIdx.x;
  const int ty = tid >> 5, tx = tid & 31;
  float acc[4][4] = {{0.f}};
  for (int k0 = 0; k0 < 1024; k0 += 32) {
    {
      int r = tid >> 3, c = (tid & 7) << 2;
      float4 v = *(const float4*)(Xb + (int64_t)(m0 + r) * 1024 + k0 + c);
      As[r][c] = v.x; As[r][c + 1] = v.y; As[r][c + 2] = v.z; As[r][c + 3] = v.w;
    }
#pragma unroll
    for (int q = 0; q < 4; ++q) {
      int r = (tid >> 5) + (q << 3);
      *(float4*)(&Bs[r][tx << 2]) =
          *(const float4*)(Ab + (int64_t)(k0 + r) * 1024 + n0 + (tx << 2));
    }
    __syncthreads();
#pragma unroll
    for (int kk = 0; kk < 32; ++kk) {
      float a_[4], b_[4];
#pragma unroll
      for (int i = 0; i < 4; ++i) a_[i] = As[ty + (i << 3)][kk];
#pragma unroll
      for (int j = 0; j < 4; ++j) b_[j] = Bs[kk][tx + (j << 5)];
#pragma unroll
      for (int i = 0; i < 4; ++i)
#pragma unroll
        for (int j = 0; j < 4; ++j) acc[i][j] = fmaf(a_[i], b_[j], acc[i][j]);
    }
    __syncthreads();
  }
#pragma unroll
  for (int i = 0; i < 4; ++i)
#pragma unroll
    for (int j = 0; j < 4; ++j)
      Y[((int64_t)b << 17) + (int64_t)(m0 + ty + (i << 3)) * 1024 + n0 + tx + (j << 5)] =
          acc[i][j];
}

// ---------------- Kernel 4: hpre[b] = W (128x384) @ concat[x0;x1;x2][b] (384x1024) + bias ----------------
__global__ __launch_bounds__(256) void k_conv(const float* __restrict__ pv,
                                              const float* __restrict__ x1,
                                              const float* __restrict__ x2,
                                              const float* __restrict__ W,
                                              const float* __restrict__ bias,
                                              float* __restrict__ hpre) {
  const int bid = blockIdx.x;
  const int b  = bid >> 5;
  const int m0 = ((bid >> 3) & 3) * 32;
  const int n0 = (bid & 7) * 128;
  const float* s0 = pv + ((int64_t)b << 17);
  const float* s1 = x1 + ((int64_t)b << 17);
  const float* s2 = x2 + ((int64_t)b << 17);
  __shared__ float As[32][33];
  __shared__ float Bs[32][128];
  const int tid = threadIdx.x;
  const int ty = tid >> 5, tx = tid & 31;
  float acc[4][4] = {{0.f}};
  for (int k0 = 0; k0 < 384; k0 += 32) {
    {
      int r = tid >> 3, c = (tid & 7) << 2;
      float4 v = *(const float4*)(W + (int64_t)(m0 + r) * 384 + k0 + c);
      As[r][c] = v.x; As[r][c + 1] = v.y; As[r][c + 2] = v.z; As[r][c + 3] = v.w;
    }
#pragma unroll
    for (int q = 0; q < 4; ++q) {
      int r = (tid >> 5) + (q << 3);
      int i = k0 + r;
      const float* src = (i < 128) ? s0 : ((i < 256) ? s1 : s2);
      *(float4*)(&Bs[r][tx << 2]) =
          *(const float4*)(src + (int64_t)(i & 127) * 1024 + n0 + (tx << 2));
    }
    __syncthreads();
#pragma unroll
    for (int kk = 0; kk < 32; ++kk) {
      float a_[4], b_[4];
#pragma unroll
      for (int i = 0; i < 4; ++i) a_[i] = As[ty + (i << 3)][kk];
#pragma unroll
      for (int j = 0; j < 4; ++j) b_[j] = Bs[kk][tx + (j << 5)];
#pragma unroll
      for (int i = 0; i < 4; ++i)
#pragma unroll
        for (int j = 0; j < 4; ++j) acc[i][j] = fmaf(a_[i], b_[j], acc[i][j]);
    }
    __syncthreads();
  }
#pragma unroll
  for (int i = 0; i < 4; ++i) {
    int o = m0 + ty + (i << 3);
    float bs = bias[o];
#pragma unroll
    for (int j = 0; j < 4; ++j)
      hpre[((int64_t)b * 128 + o) * 1024 + n0 + tx + (j << 5)] = acc[i][j] + bs;
  }
}

// ---------------- Kernel 5: per-channel BN stats (deterministic) ----------------
__global__ __launch_bounds__(256) void k_stats(const float* __restrict__ hpre,
                                               const float* __restrict__ gamma,
                                               const float* __restrict__ beta,
                                               float2* __restrict__ ss) {
  const int o = blockIdx.x;
  const int tid = threadIdx.x;
  float s = 0.f, s2 = 0.f;
  for (int e = tid; e < 8192; e += 256) {
    int bb = e >> 10, v = e & 1023;
    float val = hpre[((int64_t)(bb * 128 + o) << 10) + v];
    s += val;
    s2 = fmaf(val, val, s2);
  }
#pragma unroll
  for (int off = 1; off < 64; off <<= 1) {
    s  += __shfl_xor(s, off, 64);
    s2 += __shfl_xor(s2, off, 64);
  }
  __shared__ float rs[4], rs2[4];
  int lane = tid & 63, wid = tid >> 6;
  if (lane == 0) { rs[wid] = s; rs2[wid] = s2; }
  __syncthreads();
  if (tid == 0) {
    float S  = rs[0] + rs[1] + rs[2] + rs[3];
    float S2 = rs2[0] + rs2[1] + rs2[2] + rs2[3];
    float mean = S * (1.0f / 8192.0f);
    float var  = S2 * (1.0f / 8192.0f) - mean * mean;
    float istd = rsqrtf(var + 1e-5f);
    float scale = gamma[o] * istd;
    ss[o] = make_float2(scale, beta[o] - mean * scale);
  }
}

// ---------------- Kernel 6: BN apply + output permutation ----------------
// out[b, p*128+h, d] = hpre[b, h, 2d+p]*scale[h] + shift[h]
__global__ __launch_bounds__(256) void k_out(const float* __restrict__ hpre,
                                             const float2* __restrict__ ss,
                                             float* __restrict__ out) {
  int64_t idx = (int64_t)blockIdx.x * 256 + threadIdx.x;  // 1,048,576 total
  int d  = (int)(idx & 511);
  int ph = (int)((idx >> 9) & 255);
  int b  = (int)(idx >> 17);
  int p = ph >> 7, h = ph & 127;
  float2 sc = ss[h];
  float val = hpre[(((int64_t)b * 128 + h) << 10) + 2 * d + p];
  out[idx] = fmaf(val, sc.x, sc.y);
}

extern "C" void kernel_launch(void* const* d_in, const int* in_sizes, int n_in,
                              void* d_out, int out_size, void* d_ws, size_t ws_size,
                              hipStream_t stream) {
  const float* x     = (const float*)d_in[0];
  const float* dx    = (const float*)d_in[1];
  const float* W     = (const float*)d_in[2];
  const float* cb    = (const float*)d_in[3];
  const float* gamma = (const float*)d_in[4];
  const float* beta  = (const float*)d_in[5];

  float* ws   = (float*)d_ws;
  float* pv   = ws;                 // 1,048,576 floats
  float* Am   = pv + 1048576;       // 8,388,608 floats
  float* x1   = Am + 8388608;       // 1,048,576
  float* x2   = x1 + 1048576;       // 1,048,576
  float* hpre = x2 + 1048576;       // 1,048,576
  float2* ssb = (float2*)(hpre + 1048576);  // 128 float2
  float* out  = (float*)d_out;

  k_pool<<<2048, 256, 0, stream>>>(x, dx, pv);
  k_adj<<<1024, 256, 0, stream>>>(pv, Am);
  k_gemm_xA<<<256, 256, 0, stream>>>(pv, Am, x1);
  k_gemm_xA<<<256, 256, 0, stream>>>(x1, Am, x2);
  k_conv<<<256, 256, 0, stream>>>(pv, x1, x2, W, cb, hpre);
  k_stats<<<128, 256, 0, stream>>>(hpre, gamma, beta, ssb);
  k_out<<<4096, 256, 0, stream>>>(hpre, ssb, out);
}

// Round 3
// 169.266 us; speedup vs baseline: 2.3216x; 1.8728x over previous
//
#include <hip/hip_runtime.h>
#include <cstdint>

// Dims: B=8, H=128, D=512, L=128, V=2D=1024, inner=384
#define L_ 128

using bf16   = __bf16;
using bf16x2 = __attribute__((ext_vector_type(2))) __bf16;
using bf16x4 = __attribute__((ext_vector_type(4))) __bf16;
using bf16x8 = __attribute__((ext_vector_type(8))) __bf16;
using f32x4  = __attribute__((ext_vector_type(4))) float;

#define MFMA_B16(a, b, c) __builtin_amdgcn_mfma_f32_16x16x32_bf16((a), (b), (c), 0, 0, 0)

// ---------------- Kernel 1: argmax(|d_x|) + gather -> pv bf16 [B,H,V] ----------------
__global__ __launch_bounds__(256) void k_pool(const float* __restrict__ x,
                                              const float* __restrict__ dx,
                                              bf16* __restrict__ pvb) {
  __shared__ float lds[256][33];
  const int tid = threadIdx.x;
  const int64_t rowbase = (int64_t)blockIdx.x * 256;
  const float* dblk = dx + rowbase * 127;

  float bv = -1.0f;
  int bi = 0;

#pragma unroll
  for (int c0 = 0; c0 < 127; c0 += 32) {
    const int tw = (c0 == 96) ? 31 : 32;
    __syncthreads();
#pragma unroll
    for (int i = 0; i < 32; ++i) {
      int e = tid + (i << 8);
      int r = e >> 5;
      int cl = e & 31;
      int c = c0 + cl;
      lds[r][cl] = (c < 127) ? dblk[(int64_t)r * 127 + c] : 0.0f;
    }
    __syncthreads();
    for (int k = 0; k < tw; ++k) {
      float a = fabsf(lds[tid][k]);
      if (a > bv) { bv = a; bi = c0 + k; }
    }
  }

  const int64_t row = rowbase + tid;
  const float* xr = x + row * L_;
  float vx = xr[bi];
  float vy = xr[bi + 1];
  int64_t bh = row >> 9;
  int d = (int)(row & 511);
  bf16x2 o;
  o[0] = (bf16)vx;
  o[1] = (bf16)vy;
  *(bf16x2*)(pvb + (bh << 10) + 2 * d) = o;
}

// ---------------- Kernel 2: cast conv weights to bf16 ----------------
__global__ __launch_bounds__(256) void k_castw(const float* __restrict__ W,
                                               bf16* __restrict__ Wb) {
  int i = blockIdx.x * 256 + threadIdx.x;  // 49152 total
  Wb[i] = (bf16)W[i];
}

// ---------------- Kernel 3: transpose pvb [b][128][1024] -> XcatT[b][v][0:128] ----------------
__global__ __launch_bounds__(256) void k_tr(const bf16* __restrict__ pvb,
                                            bf16* __restrict__ XT) {
  __shared__ bf16 t[64][66];
  const int b  = blockIdx.x >> 5;
  const int hb = (blockIdx.x >> 4) & 1;
  const int vb = blockIdx.x & 15;
  const int tid = threadIdx.x;
  const bf16* src = pvb + ((int64_t)b << 17) + (int64_t)(hb << 6) * 1024 + (vb << 6);
#pragma unroll
  for (int i = 0; i < 16; ++i) {
    int e = i * 256 + tid;
    int r = e >> 6, c = e & 63;
    t[r][c] = src[(int64_t)r * 1024 + c];
  }
  __syncthreads();
  bf16* dst = XT + ((int64_t)b << 10) * 384 + (int64_t)(vb << 6) * 384 + (hb << 6);
#pragma unroll
  for (int i = 0; i < 16; ++i) {
    int e = i * 256 + tid;
    int vr = e >> 6, hc = e & 63;
    dst[(int64_t)vr * 384 + hc] = t[hc][vr];
  }
}

// ---------------- Kernel 4: adjacency via MFMA + fused softmax, writes AT bf16 ----------------
// S[v,w] = sum_h pvT[v,h]*pvT[w,h]; block = (b, 16-row v-block), 4 waves x 256 cols.
__global__ __launch_bounds__(256) void k_adj(const bf16* __restrict__ XT,
                                             bf16* __restrict__ AT) {
  const int b  = blockIdx.x >> 6;
  const int vb = blockIdx.x & 63;
  const int tid = threadIdx.x, lane = tid & 63, wid = tid >> 6;
  const int g = lane >> 4, rl = lane & 15;
  const bf16* Xb = XT + (int64_t)b * 1024 * 384;

  __shared__ bf16 lsA[16 * 128];
  __shared__ float redmax[16][4];
  __shared__ float redsum[16][4];

  {  // stage A-tile: pvT rows vb*16..+15, 128 cols, XOR-swizzled
    int row = tid >> 4, c8 = tid & 15;
    bf16x8 v = *(const bf16x8*)(Xb + (int64_t)(vb * 16 + row) * 384 + c8 * 8);
    *(bf16x8*)((char*)lsA + row * 256 + ((c8 ^ (row & 7)) << 4)) = v;
  }
  __syncthreads();

  bf16x8 af[4];
#pragma unroll
  for (int ks = 0; ks < 4; ++ks)
    af[ks] = *(const bf16x8*)((char*)lsA + rl * 256 + ((((ks << 2) | g) ^ (rl & 7)) << 4));

  f32x4 acc[16];
  f32x4 zero = {0.f, 0.f, 0.f, 0.f};
#pragma unroll
  for (int t = 0; t < 16; ++t) acc[t] = zero;

  const int nbase = wid * 256;
#pragma unroll
  for (int t = 0; t < 16; ++t) {
    const bf16* bp = Xb + (int64_t)(nbase + t * 16 + rl) * 384 + g * 8;
#pragma unroll
    for (int ks = 0; ks < 4; ++ks) {
      bf16x8 bfr = *(const bf16x8*)(bp + ks * 32);
      acc[t] = MFMA_B16(af[ks], bfr, acc[t]);
    }
  }

  // scale, mask diag, leaky relu; per-row (v = vb*16 + g*4 + r) reductions
  const int vg0 = vb * 16 + g * 4;
  float rmax[4] = {-1e30f, -1e30f, -1e30f, -1e30f};
#pragma unroll
  for (int t = 0; t < 16; ++t) {
    int n = nbase + t * 16 + rl;
#pragma unroll
    for (int r = 0; r < 4; ++r) {
      float a = acc[t][r] * (1.0f / 1024.0f);
      if (n == vg0 + r) a -= 1e8f;
      a = (a > 0.f) ? a : 0.01f * a;
      acc[t][r] = a;
      rmax[r] = fmaxf(rmax[r], a);
    }
  }
#pragma unroll
  for (int r = 0; r < 4; ++r)
#pragma unroll
    for (int off = 1; off < 16; off <<= 1)
      rmax[r] = fmaxf(rmax[r], __shfl_xor(rmax[r], off, 64));
  if (rl == 0)
#pragma unroll
    for (int r = 0; r < 4; ++r) redmax[g * 4 + r][wid] = rmax[r];
  __syncthreads();
#pragma unroll
  for (int r = 0; r < 4; ++r)
    rmax[r] = fmaxf(fmaxf(redmax[g * 4 + r][0], redmax[g * 4 + r][1]),
                    fmaxf(redmax[g * 4 + r][2], redmax[g * 4 + r][3]));

  float rsum[4] = {0.f, 0.f, 0.f, 0.f};
#pragma unroll
  for (int t = 0; t < 16; ++t)
#pragma unroll
    for (int r = 0; r < 4; ++r) {
      float e = __expf(acc[t][r] - rmax[r]);
      acc[t][r] = e;
      rsum[r] += e;
    }
#pragma unroll
  for (int r = 0; r < 4; ++r)
#pragma unroll
    for (int off = 1; off < 16; off <<= 1) rsum[r] += __shfl_xor(rsum[r], off, 64);
  if (rl == 0)
#pragma unroll
    for (int r = 0; r < 4; ++r) redsum[g * 4 + r][wid] = rsum[r];
  __syncthreads();
#pragma unroll
  for (int r = 0; r < 4; ++r) {
    float s = redsum[g * 4 + r][0] + redsum[g * 4 + r][1] +
              redsum[g * 4 + r][2] + redsum[g * 4 + r][3];
    rsum[r] = 1.0f / s;
  }

  // write AT[n][v] (transposed adjacency, bf16): lane writes 4 consecutive v
  bf16* ATb = AT + ((int64_t)b << 20);
#pragma unroll
  for (int t = 0; t < 16; ++t) {
    int n = nbase + t * 16 + rl;
    bf16x4 o;
#pragma unroll
    for (int r = 0; r < 4; ++r) {
      float v = acc[t][r] * rsum[r] + ((n == vg0 + r) ? 1.0f : 0.0f);
      o[r] = (bf16)v;
    }
    *(bf16x4*)(ATb + (int64_t)n * 1024 + vb * 16 + g * 4) = o;
  }
}

// ---------------- Kernel 5: Y = Xa(128x1024) @ A via AT; writes Yrow bf16 and/or XcatT col-slice ----------------
// Block: M=128 x N=64, 4 waves stacked along M (each 32x64). K=1024, BK=64.
template <int WRITE_ROW, int TCOL>
__global__ __launch_bounds__(256) void k_gemm(const bf16* __restrict__ Xa,
                                              const bf16* __restrict__ AT,
                                              bf16* __restrict__ Yrow,
                                              bf16* __restrict__ XT) {
  const int b  = blockIdx.x >> 4;
  const int n0 = (blockIdx.x & 15) << 6;
  const int tid = threadIdx.x, lane = tid & 63, wid = tid >> 6;
  const int g = lane >> 4, rl = lane & 15;
  const bf16* Xb = Xa + ((int64_t)b << 17);
  const bf16* Ab = AT + ((int64_t)b << 20);

  __shared__ bf16 lsA[128 * 64];
  __shared__ bf16 lsB[64 * 64];

  bf16x8 stA[4], stB[2];

  auto LOAD = [&](int ks) {
    const int k0 = ks << 6;
#pragma unroll
    for (int i = 0; i < 4; ++i) {
      int f = i * 256 + tid;
      int row = f >> 3, c8 = f & 7;
      stA[i] = *(const bf16x8*)(Xb + (int64_t)row * 1024 + k0 + c8 * 8);
    }
#pragma unroll
    for (int i = 0; i < 2; ++i) {
      int f = i * 256 + tid;
      int row = f >> 3, c8 = f & 7;
      stB[i] = *(const bf16x8*)(Ab + (int64_t)(n0 + row) * 1024 + k0 + c8 * 8);
    }
  };
  auto WRITE = [&]() {
#pragma unroll
    for (int i = 0; i < 4; ++i) {
      int f = i * 256 + tid;
      int row = f >> 3, c8 = f & 7;
      *(bf16x8*)((char*)lsA + row * 128 + ((c8 ^ (row & 7)) << 4)) = stA[i];
    }
#pragma unroll
    for (int i = 0; i < 2; ++i) {
      int f = i * 256 + tid;
      int row = f >> 3, c8 = f & 7;
      *(bf16x8*)((char*)lsB + row * 128 + ((c8 ^ (row & 7)) << 4)) = stB[i];
    }
  };

  f32x4 acc[2][4];
  f32x4 zero = {0.f, 0.f, 0.f, 0.f};
#pragma unroll
  for (int mi = 0; mi < 2; ++mi)
#pragma unroll
    for (int ni = 0; ni < 4; ++ni) acc[mi][ni] = zero;

  LOAD(0);
  WRITE();
  __syncthreads();

  for (int ks = 0; ks < 16; ++ks) {
    bf16x8 afr[2][2], bfr[4][2];
#pragma unroll
    for (int mi = 0; mi < 2; ++mi)
#pragma unroll
      for (int ku = 0; ku < 2; ++ku) {
        int row = wid * 32 + mi * 16 + rl;
        afr[mi][ku] = *(const bf16x8*)((char*)lsA + row * 128 +
                                       ((((ku << 2) | g) ^ (rl & 7)) << 4));
      }
#pragma unroll
    for (int ni = 0; ni < 4; ++ni)
#pragma unroll
      for (int ku = 0; ku < 2; ++ku) {
        int row = ni * 16 + rl;
        bfr[ni][ku] = *(const bf16x8*)((char*)lsB + row * 128 +
                                       ((((ku << 2) | g) ^ (rl & 7)) << 4));
      }
    if (ks < 15) LOAD(ks + 1);
    __syncthreads();
    if (ks < 15) WRITE();
#pragma unroll
    for (int ku = 0; ku < 2; ++ku)
#pragma unroll
      for (int mi = 0; mi < 2; ++mi)
#pragma unroll
        for (int ni = 0; ni < 4; ++ni)
          acc[mi][ni] = MFMA_B16(afr[mi][ku], bfr[ni][ku], acc[mi][ni]);
    __syncthreads();
  }

#pragma unroll
  for (int mi = 0; mi < 2; ++mi)
#pragma unroll
    for (int ni = 0; ni < 4; ++ni) {
      int c0 = wid * 32 + mi * 16 + g * 4;
      int w  = n0 + ni * 16 + rl;
      if (WRITE_ROW) {
#pragma unroll
        for (int q = 0; q < 4; ++q)
          Yrow[((int64_t)b << 17) + (int64_t)(c0 + q) * 1024 + w] = (bf16)acc[mi][ni][q];
      }
      bf16x4 o;
#pragma unroll
      for (int q = 0; q < 4; ++q) o[q] = (bf16)acc[mi][ni][q];
      *(bf16x4*)(XT + ((int64_t)b * 1024 + w) * 384 + TCOL + c0) = o;
    }
}

// ---------------- Kernel 6: h = Wb(128x384) @ XcatT^T + bias, f32 out ----------------
__global__ __launch_bounds__(256) void k_conv(const bf16* __restrict__ Wb,
                                              const bf16* __restrict__ XT,
                                              const float* __restrict__ bias,
                                              float* __restrict__ h) {
  const int b  = blockIdx.x >> 4;
  const int n0 = (blockIdx.x & 15) << 6;
  const int tid = threadIdx.x, lane = tid & 63, wid = tid >> 6;
  const int g = lane >> 4, rl = lane & 15;
  const bf16* Xb = XT + (int64_t)b * 1024 * 384;

  __shared__ bf16 lsA[128 * 64];
  __shared__ bf16 lsB[64 * 64];

  bf16x8 stA[4], stB[2];

  auto LOAD = [&](int ks) {
    const int k0 = ks << 6;
#pragma unroll
    for (int i = 0; i < 4; ++i) {
      int f = i * 256 + tid;
      int row = f >> 3, c8 = f & 7;
      stA[i] = *(const bf16x8*)(Wb + (int64_t)row * 384 + k0 + c8 * 8);
    }
#pragma unroll
    for (int i = 0; i < 2; ++i) {
      int f = i * 256 + tid;
      int row = f >> 3, c8 = f & 7;
      stB[i] = *(const bf16x8*)(Xb + (int64_t)(n0 + row) * 384 + k0 + c8 * 8);
    }
  };
  auto WRITE = [&]() {
#pragma unroll
    for (int i = 0; i < 4; ++i) {
      int f = i * 256 + tid;
      int row = f >> 3, c8 = f & 7;
      *(bf16x8*)((char*)lsA + row * 128 + ((c8 ^ (row & 7)) << 4)) = stA[i];
    }
#pragma unroll
    for (int i = 0; i < 2; ++i) {
      int f = i * 256 + tid;
      int row = f >> 3, c8 = f & 7;
      *(bf16x8*)((char*)lsB + row * 128 + ((c8 ^ (row & 7)) << 4)) = stB[i];
    }
  };

  f32x4 acc[2][4];
  f32x4 zero = {0.f, 0.f, 0.f, 0.f};
#pragma unroll
  for (int mi = 0; mi < 2; ++mi)
#pragma unroll
    for (int ni = 0; ni < 4; ++ni) acc[mi][ni] = zero;

  LOAD(0);
  WRITE();
  __syncthreads();

  for (int ks = 0; ks < 6; ++ks) {
    bf16x8 afr[2][2], bfr[4][2];
#pragma unroll
    for (int mi = 0; mi < 2; ++mi)
#pragma unroll
      for (int ku = 0; ku < 2; ++ku) {
        int row = wid * 32 + mi * 16 + rl;
        afr[mi][ku] = *(const bf16x8*)((char*)lsA + row * 128 +
                                       ((((ku << 2) | g) ^ (rl & 7)) << 4));
      }
#pragma unroll
    for (int ni = 0; ni < 4; ++ni)
#pragma unroll
      for (int ku = 0; ku < 2; ++ku) {
        int row = ni * 16 + rl;
        bfr[ni][ku] = *(const bf16x8*)((char*)lsB + row * 128 +
                                       ((((ku << 2) | g) ^ (rl & 7)) << 4));
      }
    if (ks < 5) LOAD(ks + 1);
    __syncthreads();
    if (ks < 5) WRITE();
#pragma unroll
    for (int ku = 0; ku < 2; ++ku)
#pragma unroll
      for (int mi = 0; mi < 2; ++mi)
#pragma unroll
        for (int ni = 0; ni < 4; ++ni)
          acc[mi][ni] = MFMA_B16(afr[mi][ku], bfr[ni][ku], acc[mi][ni]);
    __syncthreads();
  }

#pragma unroll
  for (int mi = 0; mi < 2; ++mi)
#pragma unroll
    for (int ni = 0; ni < 4; ++ni) {
      int c0 = wid * 32 + mi * 16 + g * 4;
      int w  = n0 + ni * 16 + rl;
#pragma unroll
      for (int q = 0; q < 4; ++q)
        h[((int64_t)(b * 128 + c0 + q) << 10) + w] = acc[mi][ni][q] + bias[c0 + q];
    }
}

// ---------------- Kernel 7: per-channel BN stats (deterministic) ----------------
__global__ __launch_bounds__(256) void k_stats(const float* __restrict__ hpre,
                                               const float* __restrict__ gamma,
                                               const float* __restrict__ beta,
                                               float2* __restrict__ ss) {
  const int o = blockIdx.x;
  const int tid = threadIdx.x;
  float s = 0.f, s2 = 0.f;
  for (int e = tid; e < 8192; e += 256) {
    int bb = e >> 10, v = e & 1023;
    float val = hpre[((int64_t)(bb * 128 + o) << 10) + v];
    s += val;
    s2 = fmaf(val, val, s2);
  }
#pragma unroll
  for (int off = 1; off < 64; off <<= 1) {
    s  += __shfl_xor(s, off, 64);
    s2 += __shfl_xor(s2, off, 64);
  }
  __shared__ float rs[4], rs2[4];
  int lane = tid & 63, wid = tid >> 6;
  if (lane == 0) { rs[wid] = s; rs2[wid] = s2; }
  __syncthreads();
  if (tid == 0) {
    float S  = rs[0] + rs[1] + rs[2] + rs[3];
    float S2 = rs2[0] + rs2[1] + rs2[2] + rs2[3];
    float mean = S * (1.0f / 8192.0f);
    float var  = S2 * (1.0f / 8192.0f) - mean * mean;
    float istd = rsqrtf(var + 1e-5f);
    float scale = gamma[o] * istd;
    ss[o] = make_float2(scale, beta[o] - mean * scale);
  }
}

// ---------------- Kernel 8: BN apply + output permutation ----------------
__global__ __launch_bounds__(256) void k_out(const float* __restrict__ hpre,
                                             const float2* __restrict__ ss,
                                             float* __restrict__ out) {
  int64_t idx = (int64_t)blockIdx.x * 256 + threadIdx.x;  // 1,048,576 total
  int d  = (int)(idx & 511);
  int ph = (int)((idx >> 9) & 255);
  int b  = (int)(idx >> 17);
  int p = ph >> 7, h = ph & 127;
  float2 sc = ss[h];
  float val = hpre[(((int64_t)b * 128 + h) << 10) + 2 * d + p];
  out[idx] = fmaf(val, sc.x, sc.y);
}

extern "C" void kernel_launch(void* const* d_in, const int* in_sizes, int n_in,
                              void* d_out, int out_size, void* d_ws, size_t ws_size,
                              hipStream_t stream) {
  const float* x     = (const float*)d_in[0];
  const float* dx    = (const float*)d_in[1];
  const float* W     = (const float*)d_in[2];
  const float* cb    = (const float*)d_in[3];
  const float* gamma = (const float*)d_in[4];
  const float* beta  = (const float*)d_in[5];

  char* ws = (char*)d_ws;
  bf16*   XcatT = (bf16*)(ws);                    //  6,291,456 B  [8][1024][384]
  bf16*   AT    = (bf16*)(ws + 6291456);          // 16,777,216 B  [8][1024][1024]
  bf16*   pvb   = (bf16*)(ws + 23068672);         //  2,097,152 B  [8][128][1024]
  bf16*   x1b   = (bf16*)(ws + 25165824);         //  2,097,152 B  [8][128][1024]
  bf16*   Wb    = (bf16*)(ws + 27262976);         //     98,304 B  [128][384]
  float*  h     = (float*)(ws + 27361280);        //  4,194,304 B  [8][128][1024]
  float2* ssb   = (float2*)(ws + 31555584);       //      1,024 B
  float* out    = (float*)d_out;

  k_pool<<<2048, 256, 0, stream>>>(x, dx, pvb);
  k_castw<<<192, 256, 0, stream>>>(W, Wb);
  k_tr<<<256, 256, 0, stream>>>(pvb, XcatT);
  k_adj<<<512, 256, 0, stream>>>(XcatT, AT);
  k_gemm<1, 128><<<128, 256, 0, stream>>>(pvb, AT, x1b, XcatT);
  k_gemm<0, 256><<<128, 256, 0, stream>>>(x1b, AT, nullptr, XcatT);
  k_conv<<<128, 256, 0, stream>>>(Wb, XcatT, cb, h);
  k_stats<<<128, 256, 0, stream>>>(h, gamma, beta, ssb);
  k_out<<<4096, 256, 0, stream>>>(h, ssb, out);
}

// Round 4
// 148.599 us; speedup vs baseline: 2.6445x; 1.1391x over previous
//
#include <hip/hip_runtime.h>
#include <cstdint>

// Dims: B=8, H=128, D=512, L=128, V=2D=1024, inner=384
#define L_ 128

using bf16   = __bf16;
using bf16x2 = __attribute__((ext_vector_type(2))) __bf16;
using bf16x4 = __attribute__((ext_vector_type(4))) __bf16;
using bf16x8 = __attribute__((ext_vector_type(8))) __bf16;
using f32x4  = __attribute__((ext_vector_type(4))) float;

#define MFMA_B16(a, b, c) __builtin_amdgcn_mfma_f32_16x16x32_bf16((a), (b), (c), 0, 0, 0)

// ---------------- Kernel 1: argmax(|d_x|) + gather -> pv bf16 [B,H,V] ----------------
// 4 lanes per row; lane j scans cols {4i+j}. Quad reduce via shfl_xor with
// (val,idx) lexicographic compare == np.argmax first-max-wins semantics.
// No LDS -> full occupancy; 32 unrolled independent loads -> latency hidden.
__global__ __launch_bounds__(256) void k_pool(const float* __restrict__ x,
                                              const float* __restrict__ dx,
                                              bf16* __restrict__ pvb) {
  const int64_t gt = (int64_t)blockIdx.x * 256 + threadIdx.x;
  const int64_t row = gt >> 2;
  const int j = (int)(gt & 3);
  const float* rp = dx + row * 127;

  float bv = -1.0f;
  int bi = 0;
#pragma unroll
  for (int i = 0; i < 32; ++i) {
    int col = 4 * i + j;
    if (col < 127) {
      float a = fabsf(rp[col]);
      if (a > bv) { bv = a; bi = col; }
    }
  }
#pragma unroll
  for (int off = 1; off <= 2; off <<= 1) {
    float ov = __shfl_xor(bv, off, 64);
    int   oi = __shfl_xor(bi, off, 64);
    if (ov > bv || (ov == bv && oi < bi)) { bv = ov; bi = oi; }
  }
  if (j == 0) {
    const float* xr = x + row * L_;
    bf16x2 o;
    o[0] = (bf16)xr[bi];
    o[1] = (bf16)xr[bi + 1];
    int64_t bh = row >> 9;
    int d = (int)(row & 511);
    *(bf16x2*)(pvb + (bh << 10) + 2 * d) = o;
  }
}

// ---------------- Kernel 2: transpose pvb [b][128][1024] -> XcatT[b][v][0:128] ----------------
__global__ __launch_bounds__(256) void k_tr(const bf16* __restrict__ pvb,
                                            bf16* __restrict__ XT) {
  __shared__ bf16 t[64][66];
  const int b  = blockIdx.x >> 5;
  const int hb = (blockIdx.x >> 4) & 1;
  const int vb = blockIdx.x & 15;
  const int tid = threadIdx.x;
  const bf16* src = pvb + ((int64_t)b << 17) + (int64_t)(hb << 6) * 1024 + (vb << 6);
#pragma unroll
  for (int i = 0; i < 16; ++i) {
    int e = i * 256 + tid;
    int r = e >> 6, c = e & 63;
    t[r][c] = src[(int64_t)r * 1024 + c];
  }
  __syncthreads();
  bf16* dst = XT + ((int64_t)b << 10) * 384 + (int64_t)(vb << 6) * 384 + (hb << 6);
#pragma unroll
  for (int i = 0; i < 16; ++i) {
    int e = i * 256 + tid;
    int vr = e >> 6, hc = e & 63;
    dst[(int64_t)vr * 384 + hc] = t[hc][vr];
  }
}

// ---------------- Kernel 3: adjacency via MFMA + fused softmax, writes AT bf16 ----------------
__global__ __launch_bounds__(256) void k_adj(const bf16* __restrict__ XT,
                                             bf16* __restrict__ AT) {
  const int b  = blockIdx.x >> 6;
  const int vb = blockIdx.x & 63;
  const int tid = threadIdx.x, lane = tid & 63, wid = tid >> 6;
  const int g = lane >> 4, rl = lane & 15;
  const bf16* Xb = XT + (int64_t)b * 1024 * 384;

  __shared__ bf16 lsA[16 * 128];
  __shared__ float redmax[16][4];
  __shared__ float redsum[16][4];

  {  // stage A-tile: pvT rows vb*16..+15, 128 cols, XOR-swizzled
    int row = tid >> 4, c8 = tid & 15;
    bf16x8 v = *(const bf16x8*)(Xb + (int64_t)(vb * 16 + row) * 384 + c8 * 8);
    *(bf16x8*)((char*)lsA + row * 256 + ((c8 ^ (row & 7)) << 4)) = v;
  }
  __syncthreads();

  bf16x8 af[4];
#pragma unroll
  for (int ks = 0; ks < 4; ++ks)
    af[ks] = *(const bf16x8*)((char*)lsA + rl * 256 + ((((ks << 2) | g) ^ (rl & 7)) << 4));

  f32x4 acc[16];
  f32x4 zero = {0.f, 0.f, 0.f, 0.f};
#pragma unroll
  for (int t = 0; t < 16; ++t) acc[t] = zero;

  const int nbase = wid * 256;
#pragma unroll
  for (int t = 0; t < 16; ++t) {
    const bf16* bp = Xb + (int64_t)(nbase + t * 16 + rl) * 384 + g * 8;
#pragma unroll
    for (int ks = 0; ks < 4; ++ks) {
      bf16x8 bfr = *(const bf16x8*)(bp + ks * 32);
      acc[t] = MFMA_B16(af[ks], bfr, acc[t]);
    }
  }

  const int vg0 = vb * 16 + g * 4;
  float rmax[4] = {-1e30f, -1e30f, -1e30f, -1e30f};
#pragma unroll
  for (int t = 0; t < 16; ++t) {
    int n = nbase + t * 16 + rl;
#pragma unroll
    for (int r = 0; r < 4; ++r) {
      float a = acc[t][r] * (1.0f / 1024.0f);
      if (n == vg0 + r) a -= 1e8f;
      a = (a > 0.f) ? a : 0.01f * a;
      acc[t][r] = a;
      rmax[r] = fmaxf(rmax[r], a);
    }
  }
#pragma unroll
  for (int r = 0; r < 4; ++r)
#pragma unroll
    for (int off = 1; off < 16; off <<= 1)
      rmax[r] = fmaxf(rmax[r], __shfl_xor(rmax[r], off, 64));
  if (rl == 0)
#pragma unroll
    for (int r = 0; r < 4; ++r) redmax[g * 4 + r][wid] = rmax[r];
  __syncthreads();
#pragma unroll
  for (int r = 0; r < 4; ++r)
    rmax[r] = fmaxf(fmaxf(redmax[g * 4 + r][0], redmax[g * 4 + r][1]),
                    fmaxf(redmax[g * 4 + r][2], redmax[g * 4 + r][3]));

  float rsum[4] = {0.f, 0.f, 0.f, 0.f};
#pragma unroll
  for (int t = 0; t < 16; ++t)
#pragma unroll
    for (int r = 0; r < 4; ++r) {
      float e = __expf(acc[t][r] - rmax[r]);
      acc[t][r] = e;
      rsum[r] += e;
    }
#pragma unroll
  for (int r = 0; r < 4; ++r)
#pragma unroll
    for (int off = 1; off < 16; off <<= 1) rsum[r] += __shfl_xor(rsum[r], off, 64);
  if (rl == 0)
#pragma unroll
    for (int r = 0; r < 4; ++r) redsum[g * 4 + r][wid] = rsum[r];
  __syncthreads();
#pragma unroll
  for (int r = 0; r < 4; ++r) {
    float s = redsum[g * 4 + r][0] + redsum[g * 4 + r][1] +
              redsum[g * 4 + r][2] + redsum[g * 4 + r][3];
    rsum[r] = 1.0f / s;
  }

  bf16* ATb = AT + ((int64_t)b << 20);
#pragma unroll
  for (int t = 0; t < 16; ++t) {
    int n = nbase + t * 16 + rl;
    bf16x4 o;
#pragma unroll
    for (int r = 0; r < 4; ++r) {
      float v = acc[t][r] * rsum[r] + ((n == vg0 + r) ? 1.0f : 0.0f);
      o[r] = (bf16)v;
    }
    *(bf16x4*)(ATb + (int64_t)n * 1024 + vb * 16 + g * 4) = o;
  }
}

// ---------------- Kernel 4: Y = Xa(128x1024) @ A via AT; writes Yrow bf16 and/or XcatT col-slice ----------------
template <int WRITE_ROW, int TCOL>
__global__ __launch_bounds__(256) void k_gemm(const bf16* __restrict__ Xa,
                                              const bf16* __restrict__ AT,
                                              bf16* __restrict__ Yrow,
                                              bf16* __restrict__ XT) {
  const int b  = blockIdx.x >> 4;
  const int n0 = (blockIdx.x & 15) << 6;
  const int tid = threadIdx.x, lane = tid & 63, wid = tid >> 6;
  const int g = lane >> 4, rl = lane & 15;
  const bf16* Xb = Xa + ((int64_t)b << 17);
  const bf16* Ab = AT + ((int64_t)b << 20);

  __shared__ bf16 lsA[128 * 64];
  __shared__ bf16 lsB[64 * 64];

  bf16x8 stA[4], stB[2];

  auto LOAD = [&](int ks) {
    const int k0 = ks << 6;
#pragma unroll
    for (int i = 0; i < 4; ++i) {
      int f = i * 256 + tid;
      int row = f >> 3, c8 = f & 7;
      stA[i] = *(const bf16x8*)(Xb + (int64_t)row * 1024 + k0 + c8 * 8);
    }
#pragma unroll
    for (int i = 0; i < 2; ++i) {
      int f = i * 256 + tid;
      int row = f >> 3, c8 = f & 7;
      stB[i] = *(const bf16x8*)(Ab + (int64_t)(n0 + row) * 1024 + k0 + c8 * 8);
    }
  };
  auto WRITE = [&]() {
#pragma unroll
    for (int i = 0; i < 4; ++i) {
      int f = i * 256 + tid;
      int row = f >> 3, c8 = f & 7;
      *(bf16x8*)((char*)lsA + row * 128 + ((c8 ^ (row & 7)) << 4)) = stA[i];
    }
#pragma unroll
    for (int i = 0; i < 2; ++i) {
      int f = i * 256 + tid;
      int row = f >> 3, c8 = f & 7;
      *(bf16x8*)((char*)lsB + row * 128 + ((c8 ^ (row & 7)) << 4)) = stB[i];
    }
  };

  f32x4 acc[2][4];
  f32x4 zero = {0.f, 0.f, 0.f, 0.f};
#pragma unroll
  for (int mi = 0; mi < 2; ++mi)
#pragma unroll
    for (int ni = 0; ni < 4; ++ni) acc[mi][ni] = zero;

  LOAD(0);
  WRITE();
  __syncthreads();

  for (int ks = 0; ks < 16; ++ks) {
    bf16x8 afr[2][2], bfr[4][2];
#pragma unroll
    for (int mi = 0; mi < 2; ++mi)
#pragma unroll
      for (int ku = 0; ku < 2; ++ku) {
        int row = wid * 32 + mi * 16 + rl;
        afr[mi][ku] = *(const bf16x8*)((char*)lsA + row * 128 +
                                       ((((ku << 2) | g) ^ (rl & 7)) << 4));
      }
#pragma unroll
    for (int ni = 0; ni < 4; ++ni)
#pragma unroll
      for (int ku = 0; ku < 2; ++ku) {
        int row = ni * 16 + rl;
        bfr[ni][ku] = *(const bf16x8*)((char*)lsB + row * 128 +
                                       ((((ku << 2) | g) ^ (rl & 7)) << 4));
      }
    if (ks < 15) LOAD(ks + 1);
    __syncthreads();
    if (ks < 15) WRITE();
#pragma unroll
    for (int ku = 0; ku < 2; ++ku)
#pragma unroll
      for (int mi = 0; mi < 2; ++mi)
#pragma unroll
        for (int ni = 0; ni < 4; ++ni)
          acc[mi][ni] = MFMA_B16(afr[mi][ku], bfr[ni][ku], acc[mi][ni]);
    __syncthreads();
  }

#pragma unroll
  for (int mi = 0; mi < 2; ++mi)
#pragma unroll
    for (int ni = 0; ni < 4; ++ni) {
      int c0 = wid * 32 + mi * 16 + g * 4;
      int w  = n0 + ni * 16 + rl;
      if (WRITE_ROW) {
#pragma unroll
        for (int q = 0; q < 4; ++q)
          Yrow[((int64_t)b << 17) + (int64_t)(c0 + q) * 1024 + w] = (bf16)acc[mi][ni][q];
      }
      bf16x4 o;
#pragma unroll
      for (int q = 0; q < 4; ++q) o[q] = (bf16)acc[mi][ni][q];
      *(bf16x4*)(XT + ((int64_t)b * 1024 + w) * 384 + TCOL + c0) = o;
    }
}

// ---------------- Kernel 5: h = W(128x384, f32 cast on the fly) @ XcatT^T + bias ----------------
__global__ __launch_bounds__(256) void k_conv(const float* __restrict__ W,
                                              const bf16* __restrict__ XT,
                                              const float* __restrict__ bias,
                                              float* __restrict__ h) {
  const int b  = blockIdx.x >> 4;
  const int n0 = (blockIdx.x & 15) << 6;
  const int tid = threadIdx.x, lane = tid & 63, wid = tid >> 6;
  const int g = lane >> 4, rl = lane & 15;
  const bf16* Xb = XT + (int64_t)b * 1024 * 384;

  __shared__ bf16 lsA[128 * 64];
  __shared__ bf16 lsB[64 * 64];

  bf16x8 stA[4], stB[2];

  auto LOAD = [&](int ks) {
    const int k0 = ks << 6;
#pragma unroll
    for (int i = 0; i < 4; ++i) {
      int f = i * 256 + tid;
      int row = f >> 3, c8 = f & 7;
      const float* wp = W + (int64_t)row * 384 + k0 + c8 * 8;
      float4 a0 = *(const float4*)(wp);
      float4 a1 = *(const float4*)(wp + 4);
      bf16x8 r;
      r[0] = (bf16)a0.x; r[1] = (bf16)a0.y; r[2] = (bf16)a0.z; r[3] = (bf16)a0.w;
      r[4] = (bf16)a1.x; r[5] = (bf16)a1.y; r[6] = (bf16)a1.z; r[7] = (bf16)a1.w;
      stA[i] = r;
    }
#pragma unroll
    for (int i = 0; i < 2; ++i) {
      int f = i * 256 + tid;
      int row = f >> 3, c8 = f & 7;
      stB[i] = *(const bf16x8*)(Xb + (int64_t)(n0 + row) * 384 + k0 + c8 * 8);
    }
  };
  auto WRITE = [&]() {
#pragma unroll
    for (int i = 0; i < 4; ++i) {
      int f = i * 256 + tid;
      int row = f >> 3, c8 = f & 7;
      *(bf16x8*)((char*)lsA + row * 128 + ((c8 ^ (row & 7)) << 4)) = stA[i];
    }
#pragma unroll
    for (int i = 0; i < 2; ++i) {
      int f = i * 256 + tid;
      int row = f >> 3, c8 = f & 7;
      *(bf16x8*)((char*)lsB + row * 128 + ((c8 ^ (row & 7)) << 4)) = stB[i];
    }
  };

  f32x4 acc[2][4];
  f32x4 zero = {0.f, 0.f, 0.f, 0.f};
#pragma unroll
  for (int mi = 0; mi < 2; ++mi)
#pragma unroll
    for (int ni = 0; ni < 4; ++ni) acc[mi][ni] = zero;

  LOAD(0);
  WRITE();
  __syncthreads();

  for (int ks = 0; ks < 6; ++ks) {
    bf16x8 afr[2][2], bfr[4][2];
#pragma unroll
    for (int mi = 0; mi < 2; ++mi)
#pragma unroll
      for (int ku = 0; ku < 2; ++ku) {
        int row = wid * 32 + mi * 16 + rl;
        afr[mi][ku] = *(const bf16x8*)((char*)lsA + row * 128 +
                                       ((((ku << 2) | g) ^ (rl & 7)) << 4));
      }
#pragma unroll
    for (int ni = 0; ni < 4; ++ni)
#pragma unroll
      for (int ku = 0; ku < 2; ++ku) {
        int row = ni * 16 + rl;
        bfr[ni][ku] = *(const bf16x8*)((char*)lsB + row * 128 +
                                       ((((ku << 2) | g) ^ (rl & 7)) << 4));
      }
    if (ks < 5) LOAD(ks + 1);
    __syncthreads();
    if (ks < 5) WRITE();
#pragma unroll
    for (int ku = 0; ku < 2; ++ku)
#pragma unroll
      for (int mi = 0; mi < 2; ++mi)
#pragma unroll
        for (int ni = 0; ni < 4; ++ni)
          acc[mi][ni] = MFMA_B16(afr[mi][ku], bfr[ni][ku], acc[mi][ni]);
    __syncthreads();
  }

#pragma unroll
  for (int mi = 0; mi < 2; ++mi)
#pragma unroll
    for (int ni = 0; ni < 4; ++ni) {
      int c0 = wid * 32 + mi * 16 + g * 4;
      int w  = n0 + ni * 16 + rl;
#pragma unroll
      for (int q = 0; q < 4; ++q)
        h[((int64_t)(b * 128 + c0 + q) << 10) + w] = acc[mi][ni][q] + bias[c0 + q];
    }
}

// ---------------- Kernel 6: per-channel BN stats (deterministic) ----------------
__global__ __launch_bounds__(256) void k_stats(const float* __restrict__ hpre,
                                               const float* __restrict__ gamma,
                                               const float* __restrict__ beta,
                                               float2* __restrict__ ss) {
  const int o = blockIdx.x;
  const int tid = threadIdx.x;
  float s = 0.f, s2 = 0.f;
  for (int e = tid; e < 8192; e += 256) {
    int bb = e >> 10, v = e & 1023;
    float val = hpre[((int64_t)(bb * 128 + o) << 10) + v];
    s += val;
    s2 = fmaf(val, val, s2);
  }
#pragma unroll
  for (int off = 1; off < 64; off <<= 1) {
    s  += __shfl_xor(s, off, 64);
    s2 += __shfl_xor(s2, off, 64);
  }
  __shared__ float rs[4], rs2[4];
  int lane = tid & 63, wid = tid >> 6;
  if (lane == 0) { rs[wid] = s; rs2[wid] = s2; }
  __syncthreads();
  if (tid == 0) {
    float S  = rs[0] + rs[1] + rs[2] + rs[3];
    float S2 = rs2[0] + rs2[1] + rs2[2] + rs2[3];
    float mean = S * (1.0f / 8192.0f);
    float var  = S2 * (1.0f / 8192.0f) - mean * mean;
    float istd = rsqrtf(var + 1e-5f);
    float scale = gamma[o] * istd;
    ss[o] = make_float2(scale, beta[o] - mean * scale);
  }
}

// ---------------- Kernel 7: BN apply + output permutation ----------------
__global__ __launch_bounds__(256) void k_out(const float* __restrict__ hpre,
                                             const float2* __restrict__ ss,
                                             float* __restrict__ out) {
  int64_t idx = (int64_t)blockIdx.x * 256 + threadIdx.x;  // 1,048,576 total
  int d  = (int)(idx & 511);
  int ph = (int)((idx >> 9) & 255);
  int b  = (int)(idx >> 17);
  int p = ph >> 7, h = ph & 127;
  float2 sc = ss[h];
  float val = hpre[(((int64_t)b * 128 + h) << 10) + 2 * d + p];
  out[idx] = fmaf(val, sc.x, sc.y);
}

extern "C" void kernel_launch(void* const* d_in, const int* in_sizes, int n_in,
                              void* d_out, int out_size, void* d_ws, size_t ws_size,
                              hipStream_t stream) {
  const float* x     = (const float*)d_in[0];
  const float* dx    = (const float*)d_in[1];
  const float* W     = (const float*)d_in[2];
  const float* cb    = (const float*)d_in[3];
  const float* gamma = (const float*)d_in[4];
  const float* beta  = (const float*)d_in[5];

  char* ws = (char*)d_ws;
  bf16*   XcatT = (bf16*)(ws);                    //  6,291,456 B  [8][1024][384]
  bf16*   AT    = (bf16*)(ws + 6291456);          // 16,777,216 B  [8][1024][1024]
  bf16*   pvb   = (bf16*)(ws + 23068672);         //  2,097,152 B  [8][128][1024]
  bf16*   x1b   = (bf16*)(ws + 25165824);         //  2,097,152 B  [8][128][1024]
  float*  h     = (float*)(ws + 27361280);        //  4,194,304 B  [8][128][1024]
  float2* ssb   = (float2*)(ws + 31555584);       //      1,024 B
  float* out    = (float*)d_out;

  k_pool<<<8192, 256, 0, stream>>>(x, dx, pvb);
  k_tr<<<256, 256, 0, stream>>>(pvb, XcatT);
  k_adj<<<512, 256, 0, stream>>>(XcatT, AT);
  k_gemm<1, 128><<<128, 256, 0, stream>>>(pvb, AT, x1b, XcatT);
  k_gemm<0, 256><<<128, 256, 0, stream>>>(x1b, AT, nullptr, XcatT);
  k_conv<<<128, 256, 0, stream>>>(W, XcatT, cb, h);
  k_stats<<<128, 256, 0, stream>>>(h, gamma, beta, ssb);
  k_out<<<4096, 256, 0, stream>>>(h, ssb, out);
}